// Round 14
// baseline (272.183 us; speedup 1.0000x reference)
//
#include <hip/hip_runtime.h>

#define EPSV 1e-8f
#define PW   34
#define NPIX 1024
#define NA   5
#define NOUT 17
#define NZC  150
#define NZH  75          // channels per cgroup
#define MAXS 8

// ================= K0: obs-MLP softmax weights + Z2oZ1 collapse =============
__global__ __launch_bounds__(256) void k0_prep(
    const float* __restrict__ obs_in,
    const float* __restrict__ O1_w, const float* __restrict__ O1_b,
    const float* __restrict__ O3_w, const float* __restrict__ O3_b,
    const float* __restrict__ Z1_w, const float* __restrict__ Z1_b,
    const float* __restrict__ Z2_w, const float* __restrict__ Z2_b,
    float* __restrict__ w_all, float* __restrict__ zc, int S)
{
    __shared__ float h[MAXS*NOUT], u[MAXS*NOUT];
    const int tid = threadIdx.x, b = blockIdx.x;
    const int t = tid / NOUT, o = tid % NOUT;
    const bool act = (tid < S*NOUT);

    if (act) {
        const float* ob = obs_in + (b*S + t)*4;
        float hh = O1_b[o];
        #pragma unroll
        for (int k = 0; k < 4; ++k) hh += ob[k] * O1_w[o*4 + k];
        h[tid] = tanhf(hh);
    }
    __syncthreads();
    if (act) {
        float uu = O3_b[o];
        #pragma unroll
        for (int j = 0; j < NOUT; ++j) uu += h[t*NOUT + j] * O3_w[o*NOUT + j];
        u[tid] = uu;
    }
    __syncthreads();
    if (act) {
        float mx = u[t*NOUT];
        #pragma unroll
        for (int j = 1; j < NOUT; ++j) mx = fmaxf(mx, u[t*NOUT + j]);
        float sm = 0.f;
        #pragma unroll
        for (int j = 0; j < NOUT; ++j) sm += expf(u[t*NOUT + j] - mx);
        w_all[(b*MAXS + t)*NOUT + o] = expf(u[tid] - mx) / sm;
    }
    if (b == 0) {
        for (int j2 = tid; j2 < NOUT*9 + NOUT; j2 += 256) {
            if (j2 < NOUT*9) {
                const int oo = j2 / 9, k = j2 % 9;
                float s = 0.f;
                for (int c = 0; c < NZC; ++c) s += Z2_w[oo*NZC + c] * Z1_w[c*9 + k];
                zc[j2] = s;
            } else {
                const int oo = j2 - NOUT*9;
                float s = Z2_b[oo];
                for (int c = 0; c < NZC; ++c) s += Z2_w[oo*NZC + c] * Z1_b[c];
                zc[j2] = s;
            }
        }
    }
}

// ===== K1: R-conv + Z, 2D split: 8 blocks/image = 4-row strip x 2 cgroups ===
// block: 256 threads = 128 px (tid&127) x cgroup (tid>>7). cgroup is
// wave-uniform (lanes 0..63 share tid>>7), so weight loads stay s_load.
__global__ __launch_bounds__(256, 8) void k1_rz(
    const float* __restrict__ map_in,
    const float* __restrict__ R1_w, const float* __restrict__ R1_b,
    const float* __restrict__ R2_w, const float* __restrict__ R2_b,
    const float* __restrict__ w_all, const float* __restrict__ zc,
    float* __restrict__ r_part, float* __restrict__ zo_out, int S)
{
    __shared__ float t0[6*34], t1[6*34];
    const int tid = threadIdx.x;
    const int b = blockIdx.x >> 3, strip = blockIdx.x & 7;
    const int p  = tid & 127;                 // px within strip
    const int cg = tid >> 7;                  // 0 or 1 (wave-uniform)
    const int ty = p >> 5, x = p & 31;        // ty 0..3
    const int y = strip*4 + ty;
    const int pix = y*32 + x;

    // stage 6x34 zero-padded tile (rows strip*4-1 .. strip*4+4), both channels
    for (int i = tid; i < 2*204; i += 256) {
        const int ch = i / 204, j = i % 204;
        const int tr = j / 34, tc = j % 34;
        const int gy = strip*4 - 1 + tr, gx = tc - 1;
        const bool ok = (gy >= 0 && gy < 32 && gx >= 0 && gx < 32);
        const float v = ok ? map_in[b*2*NPIX + ch*NPIX + gy*32 + gx] : 0.f;
        if (ch == 0) t0[j] = v; else t1[j] = v;
    }
    __syncthreads();

    float m0[9], m1[9];
    #pragma unroll
    for (int k = 0; k < 9; ++k) {
        const int off = (ty + k/3)*34 + x + (k%3);
        m0[k] = t0[off]; m1[k] = t1[off];
    }

    // partial R over this cgroup's 75 channels
    float r[NA];
    #pragma unroll
    for (int a = 0; a < NA; ++a) r[a] = (cg == 0) ? R2_b[a] : 0.f;
    const int c0 = cg * NZH;
    for (int c = c0; c < c0 + NZH; ++c) {
        float s = R1_b[c];
        const float* w1 = R1_w + c*18;
        #pragma unroll
        for (int k = 0; k < 9; ++k) s += m0[k] * w1[k];
        #pragma unroll
        for (int k = 0; k < 9; ++k) s += m1[k] * w1[9 + k];
        s = fmaxf(s, 0.f);
        #pragma unroll
        for (int a = 0; a < NA; ++a) r[a] += R2_w[a*NZC + c] * s;
    }
    #pragma unroll
    for (int a = 0; a < NA; ++a)
        r_part[(((size_t)b*2 + cg)*NA + a)*NPIX + pix] = r[a];

    // Z (cgroup 0 only): sigmoid(collapsed conv), normalize, fold w_t -> zo
    if (cg == 0) {
        float z[NOUT];
        float zs = 0.f;
        #pragma unroll
        for (int o = 0; o < NOUT; ++o) {
            float s = zc[NOUT*9 + o];
            #pragma unroll
            for (int k = 0; k < 9; ++k) s += m0[k] * zc[o*9 + k];
            const float zz = 1.f / (1.f + expf(-s));
            z[o] = zz; zs += zz;
        }
        const float zn = 1.f / (zs + EPSV);
        for (int t = 0; t < S; ++t) {
            float zo = 0.f;
            #pragma unroll
            for (int o = 0; o < NOUT; ++o) zo += z[o] * w_all[(b*MAXS + t)*NOUT + o];
            zo_out[((size_t)b*S + t)*NPIX + pix] = zo * zn;
        }
    }
}

// ================= K2: VI (R5 2-barrier structure) + belief =================
__global__ __launch_bounds__(1024, 4) void k2_vib(
    const float* __restrict__ b0,   const int* __restrict__ act_in,
    const int*   __restrict__ step_p, const int* __restrict__ vik_p,
    const float* __restrict__ Tb_w, const float* __restrict__ Tb_b,
    const float* __restrict__ Tv_w, const float* __restrict__ Tv_b,
    const float* __restrict__ FL_w, const float* __restrict__ FL_b,
    const float* __restrict__ r_part, const float* __restrict__ zo_in,
    float* __restrict__ out, int B)
{
    __shared__ float v_lds[PW*PW], b_lds[PW*PW];
    __shared__ float partials[16][6], sums[6];

    const int tid  = threadIdx.x;
    const int blk  = blockIdx.x;
    const int y    = tid >> 5, x = tid & 31;
    const int pidx = (y + 1) * PW + (x + 1);
    const int lane = tid & 63, wvid = tid >> 6;

    const int S = step_p[0];
    const int K = vik_p[0];

    for (int i = tid; i < PW*PW; i += NPIX) { v_lds[i] = 0.f; b_lds[i] = 0.f; }
    __syncthreads();
    b_lds[pidx] = b0[blk*NPIX + tid];

    // r = part0 + part1, Tv bias folded
    float r[NA];
    #pragma unroll
    for (int a = 0; a < NA; ++a)
        r[a] = r_part[(((size_t)blk*2 + 0)*NA + a)*NPIX + tid]
             + r_part[(((size_t)blk*2 + 1)*NA + a)*NPIX + tid]
             + Tv_b[a];

    // value iteration: single buffer, 2 barriers/iter (banked best)
    float q[NA];
    #pragma unroll
    for (int a = 0; a < NA; ++a) q[a] = 0.f;
    for (int it = 0; it < K; ++it) {
        float n[9];
        #pragma unroll
        for (int k = 0; k < 9; ++k) n[k] = v_lds[(y + k/3)*PW + x + (k%3)];
        float vmax = -3.4e38f;
        #pragma unroll
        for (int a = 0; a < NA; ++a) {
            float s = r[a];
            #pragma unroll
            for (int k = 0; k < 9; ++k) s += n[k] * Tv_w[a*9 + k];
            q[a] = s;
            vmax = fmaxf(vmax, s);
        }
        __syncthreads();
        v_lds[pidx] = vmax;
        __syncthreads();
    }

    // belief-propagation timestep loop
    for (int t = 0; t < S; ++t) {
        const int a_t = act_in[blk*S + t];
        float bp = Tb_b[a_t];
        #pragma unroll
        for (int k = 0; k < 9; ++k)
            bp += b_lds[(y + k/3)*PW + x + (k%3)] * Tb_w[a_t*9 + k];

        const float bn = bp * zo_in[((size_t)blk*S + t)*NPIX + tid];

        float v6[6];
        v6[5] = bn;
        #pragma unroll
        for (int a = 0; a < NA; ++a) v6[a] = q[a] * bn;
        #pragma unroll
        for (int k = 0; k < 6; ++k) {
            float vv = v6[k];
            for (int off = 32; off > 0; off >>= 1) vv += __shfl_down(vv, off);
            v6[k] = vv;
        }
        if (lane == 0) {
            #pragma unroll
            for (int k = 0; k < 6; ++k) partials[wvid][k] = v6[k];
        }
        __syncthreads();
        if (tid < 6) {
            float s = 0.f;
            for (int w2 = 0; w2 < 16; ++w2) s += partials[w2][tid];
            sums[tid] = s;
        }
        __syncthreads();

        const float inv = 1.f / (sums[5] + EPSV);
        if (tid < NA) {
            float oj = FL_b[tid];
            #pragma unroll
            for (int a = 0; a < NA; ++a) oj += (sums[a] * inv) * FL_w[tid*NA + a];
            out[(t*B + blk)*NA + tid] = oj;
        }
        b_lds[pidx] = bn * inv;
        __syncthreads();
    }

    out[S*B*NA + blk*NPIX + tid] = b_lds[pidx];
}

extern "C" void kernel_launch(void* const* d_in, const int* in_sizes, int n_in,
                              void* d_out, int out_size, void* d_ws, size_t ws_size,
                              hipStream_t stream)
{
    const float* map_in = (const float*)d_in[0];
    const float* b0     = (const float*)d_in[1];
    const int*   act_in = (const int*)  d_in[2];
    const float* obs_in = (const float*)d_in[3];
    const int*   step_p = (const int*)  d_in[5];
    const int*   vik_p  = (const int*)  d_in[6];
    const float* Tb_w = (const float*)d_in[7];
    const float* Tb_b = (const float*)d_in[8];
    const float* Tv_w = (const float*)d_in[9];
    const float* Tv_b = (const float*)d_in[10];
    const float* Z1_w = (const float*)d_in[11];
    const float* Z1_b = (const float*)d_in[12];
    const float* Z2_w = (const float*)d_in[13];
    const float* Z2_b = (const float*)d_in[14];
    const float* O1_w = (const float*)d_in[15];
    const float* O1_b = (const float*)d_in[16];
    const float* O3_w = (const float*)d_in[17];
    const float* O3_b = (const float*)d_in[18];
    const float* R1_w = (const float*)d_in[19];
    const float* R1_b = (const float*)d_in[20];
    const float* R2_w = (const float*)d_in[21];
    const float* R2_b = (const float*)d_in[22];
    const float* FL_w = (const float*)d_in[23];
    const float* FL_b = (const float*)d_in[24];

    const int B = in_sizes[1] / NPIX;     // b0 is (B,32,32)
    const int S = in_sizes[2] / B;        // act_in is (B,S)

    // ws (floats): w_all[B*MAXS*NOUT] | zc[192] | r_part[B*2*NA*NPIX] | zo[B*S*NPIX]
    float* ws    = (float*)d_ws;
    float* w_all = ws;
    float* zc    = w_all + (size_t)B*MAXS*NOUT;
    float* r_ws  = zc + 192;
    float* zo_ws = r_ws + (size_t)B*2*NA*NPIX;

    hipLaunchKernelGGL(k0_prep, dim3(B), dim3(256), 0, stream,
        obs_in, O1_w, O1_b, O3_w, O3_b, Z1_w, Z1_b, Z2_w, Z2_b, w_all, zc, S);

    hipLaunchKernelGGL(k1_rz, dim3(B*8), dim3(256), 0, stream,
        map_in, R1_w, R1_b, R2_w, R2_b, w_all, zc, r_ws, zo_ws, S);

    hipLaunchKernelGGL(k2_vib, dim3(B), dim3(1024), 0, stream,
        b0, act_in, step_p, vik_p, Tb_w, Tb_b, Tv_w, Tv_b, FL_w, FL_b,
        r_ws, zo_ws, (float*)d_out, B);
}

// Round 15
// 194.677 us; speedup vs baseline: 1.3981x; 1.3981x over previous
//
#include <hip/hip_runtime.h>

#define EPSV 1e-8f
#define PW   34          // 32 + 2 halo (zero pad)
#define NPIX 1024
#define NA   5
#define NOUT 17
#define NZC  150
#define MAXS 8           // max supported step_size (harness uses 4)

// block=1024 (1 image/block), 1 block/CU. R12 structure; ONE change:
// R-conv weights staged to LDS as 24-float records {W1[18],b,R2^T[5]} and
// read via ds_read_b128 broadcasts — replaces per-wave scalar streaming
// (R13/R14 evidence: scalar weight path was the R-conv bottleneck).
__global__ __launch_bounds__(1024, 4) void vin_fused(
    const float* __restrict__ map_in, const float* __restrict__ b0,
    const int*   __restrict__ act_in, const float* __restrict__ obs_in,
    const int*   __restrict__ step_p, const int*   __restrict__ vik_p,
    const float* __restrict__ Tb_w,  const float* __restrict__ Tb_b,
    const float* __restrict__ Tv_w,  const float* __restrict__ Tv_b,
    const float* __restrict__ Z1_w,  const float* __restrict__ Z1_b,
    const float* __restrict__ Z2_w,  const float* __restrict__ Z2_b,
    const float* __restrict__ O1_w,  const float* __restrict__ O1_b,
    const float* __restrict__ O3_w,  const float* __restrict__ O3_b,
    const float* __restrict__ R1_w,  const float* __restrict__ R1_b,
    const float* __restrict__ R2_w,  const float* __restrict__ R2_b,
    const float* __restrict__ FL_w,  const float* __restrict__ FL_b,
    float* __restrict__ out, int B)
{
    __shared__ float map0[PW*PW], map1[PW*PW], v_lds[PW*PW], b_lds[PW*PW];
    __shared__ float zc_w[NOUT*9], zc_b[NOUT];
    __shared__ float h_all[MAXS][NOUT], u_all[MAXS][NOUT], w_all[MAXS][NOUT];
    __shared__ float zo_lds[MAXS * NPIX];
    __shared__ float partials[16][6], sums[6];
    __shared__ __align__(16) float wrec[NZC * 24];   // {W1[18], b, R2^T[5]} per ch

    const int tid  = threadIdx.x;
    const int blk  = blockIdx.x;
    const int y    = tid >> 5, x = tid & 31;
    const int pidx = (y + 1) * PW + (x + 1);
    const int lane = tid & 63, wvid = tid >> 6;

    const int S = step_p[0];
    const int K = vik_p[0];

    // ---- init: zero-padded LDS tiles ----
    for (int i = tid; i < PW*PW; i += NPIX) {
        map0[i] = 0.f; map1[i] = 0.f; v_lds[i] = 0.f; b_lds[i] = 0.f;
    }
    __syncthreads();
    map0[pidx]  = map_in[blk*2*NPIX + tid];
    map1[pidx]  = map_in[blk*2*NPIX + NPIX + tid];
    b_lds[pidx] = b0[blk*NPIX + tid];

    // ---- stage R-conv weight records into LDS (3600 floats, 4 passes) ----
    for (int i = tid; i < NZC*24; i += NPIX) {
        const int c = i / 24, j = i % 24;
        float v;
        if (j < 18)      v = R1_w[c*18 + j];
        else if (j == 18) v = R1_b[c];
        else              v = R2_w[(j - 19)*NZC + c];
        wrec[i] = v;
    }

    // ---- collapse Z2(1x1) o Z1(3x3) into one 17-ch 3x3 conv ----
    if (tid < NOUT*9) {
        const int o = tid / 9, k = tid % 9;
        float s = 0.f;
        for (int c = 0; c < NZC; ++c) s += Z2_w[o*NZC + c] * Z1_w[c*9 + k];
        zc_w[tid] = s;
    } else if (tid < NOUT*9 + NOUT) {
        const int o = tid - NOUT*9;
        float s = Z2_b[o];
        for (int c = 0; c < NZC; ++c) s += Z2_w[o*NZC + c] * Z1_b[c];
        zc_b[o] = s;
    }

    // ---- observation MLP for ALL timesteps upfront (threads 256..256+S*17) ----
    const int mt = tid - 256;
    const int mT = mt / NOUT, mO = mt % NOUT;
    if (mt >= 0 && mt < S*NOUT) {
        const float* ob = obs_in + (blk*S + mT)*4;
        float hh = O1_b[mO];
        #pragma unroll
        for (int k = 0; k < 4; ++k) hh += ob[k] * O1_w[mO*4 + k];
        h_all[mT][mO] = tanhf(hh);
    }
    __syncthreads();
    if (mt >= 0 && mt < S*NOUT) {
        float u = O3_b[mO];
        #pragma unroll
        for (int j = 0; j < NOUT; ++j) u += h_all[mT][j] * O3_w[mO*NOUT + j];
        u_all[mT][mO] = u;
    }
    __syncthreads();
    if (mt >= 0 && mt < S*NOUT) {
        float mx = u_all[mT][0];
        #pragma unroll
        for (int j = 1; j < NOUT; ++j) mx = fmaxf(mx, u_all[mT][j]);
        float sm = 0.f;
        #pragma unroll
        for (int j = 0; j < NOUT; ++j) sm += expf(u_all[mT][j] - mx);
        w_all[mT][mO] = expf(u_all[mT][mO] - mx) / sm;
    }
    __syncthreads();

    // ---- stencil neighborhood into registers ----
    float m0[9], m1[9];
    #pragma unroll
    for (int k = 0; k < 9; ++k) {
        const int off = (y + k/3)*PW + x + (k%3);
        m0[k] = map0[off]; m1[k] = map1[off];
    }

    // ---- R = conv1x1(relu(conv3x3(map))); weights via LDS b128 broadcast ----
    float r[NA];
    #pragma unroll
    for (int a = 0; a < NA; ++a) r[a] = R2_b[a];
    for (int c = 0; c < NZC; ++c) {
        const float4* rec = reinterpret_cast<const float4*>(&wrec[c*24]);
        const float4 A = rec[0], Bq = rec[1], Cq = rec[2];
        const float4 D = rec[3], E  = rec[4], F  = rec[5];
        float s = E.z;                       // R1_b[c]
        s += m0[0]*A.x;  s += m0[1]*A.y;  s += m0[2]*A.z;  s += m0[3]*A.w;
        s += m0[4]*Bq.x; s += m0[5]*Bq.y; s += m0[6]*Bq.z; s += m0[7]*Bq.w;
        s += m0[8]*Cq.x;
        s += m1[0]*Cq.y; s += m1[1]*Cq.z; s += m1[2]*Cq.w;
        s += m1[3]*D.x;  s += m1[4]*D.y;  s += m1[5]*D.z;  s += m1[6]*D.w;
        s += m1[7]*E.x;  s += m1[8]*E.y;
        s = fmaxf(s, 0.f);
        r[0] += E.w*s; r[1] += F.x*s; r[2] += F.y*s; r[3] += F.z*s; r[4] += F.w*s;
    }

    // ---- Z: sigmoid(collapsed conv), normalized, collapsed against w_t ----
    {
        float z[NOUT];
        float zs = 0.f;
        #pragma unroll
        for (int o = 0; o < NOUT; ++o) {
            float s = zc_b[o];
            #pragma unroll
            for (int k = 0; k < 9; ++k) s += m0[k] * zc_w[o*9 + k];
            const float zz = 1.f / (1.f + expf(-s));
            z[o] = zz; zs += zz;
        }
        const float zn = 1.f / (zs + EPSV);
        for (int t = 0; t < S; ++t) {
            float zo = 0.f;
            #pragma unroll
            for (int o = 0; o < NOUT; ++o) zo += z[o] * w_all[t][o];
            zo_lds[t*NPIX + tid] = zo * zn;
        }
    }

    // ---- value iteration: single buffer, 2 barriers/iter (banked best) ----
    float q[NA];
    #pragma unroll
    for (int a = 0; a < NA; ++a) q[a] = 0.f;
    for (int it = 0; it < K; ++it) {
        float n[9];
        #pragma unroll
        for (int k = 0; k < 9; ++k) n[k] = v_lds[(y + k/3)*PW + x + (k%3)];
        float vmax = -3.4e38f;
        #pragma unroll
        for (int a = 0; a < NA; ++a) {
            float s = Tv_b[a] + r[a];
            #pragma unroll
            for (int k = 0; k < 9; ++k) s += n[k] * Tv_w[a*9 + k];
            q[a] = s;
            vmax = fmaxf(vmax, s);
        }
        __syncthreads();
        v_lds[pidx] = vmax;
        __syncthreads();
    }

    // ---- belief-propagation timestep loop ----
    for (int t = 0; t < S; ++t) {
        const int a_t = act_in[blk*S + t];     // block-uniform
        float bp = Tb_b[a_t];
        #pragma unroll
        for (int k = 0; k < 9; ++k)
            bp += b_lds[(y + k/3)*PW + x + (k%3)] * Tb_w[a_t*9 + k];

        const float bn = bp * zo_lds[t*NPIX + tid];

        // fused 6-way reduction: sums[0..4] = sum q[a]*bn, sums[5] = sum bn
        float v6[6];
        v6[5] = bn;
        #pragma unroll
        for (int a = 0; a < NA; ++a) v6[a] = q[a] * bn;
        #pragma unroll
        for (int k = 0; k < 6; ++k) {
            float vv = v6[k];
            for (int off = 32; off > 0; off >>= 1) vv += __shfl_down(vv, off);
            v6[k] = vv;
        }
        if (lane == 0) {
            #pragma unroll
            for (int k = 0; k < 6; ++k) partials[wvid][k] = v6[k];
        }
        __syncthreads();
        if (tid < 6) {
            float s = 0.f;
            for (int w2 = 0; w2 < 16; ++w2) s += partials[w2][tid];
            sums[tid] = s;
        }
        __syncthreads();

        const float inv = 1.f / (sums[5] + EPSV);
        if (tid < NA) {
            float oj = FL_b[tid];
            #pragma unroll
            for (int a = 0; a < NA; ++a) oj += (sums[a] * inv) * FL_w[tid*NA + a];
            out[(t*B + blk)*NA + tid] = oj;
        }
        b_lds[pidx] = bn * inv;   // normalized belief for next step
        __syncthreads();
    }

    // ---- final belief output ----
    out[S*B*NA + blk*NPIX + tid] = b_lds[pidx];
}

extern "C" void kernel_launch(void* const* d_in, const int* in_sizes, int n_in,
                              void* d_out, int out_size, void* d_ws, size_t ws_size,
                              hipStream_t stream)
{
    const float* map_in = (const float*)d_in[0];
    const float* b0     = (const float*)d_in[1];
    const int*   act_in = (const int*)  d_in[2];
    const float* obs_in = (const float*)d_in[3];
    // d_in[4] = is_start (unused: reference uses b0 either way)
    const int*   step_p = (const int*)  d_in[5];
    const int*   vik_p  = (const int*)  d_in[6];
    const float* Tb_w = (const float*)d_in[7];
    const float* Tb_b = (const float*)d_in[8];
    const float* Tv_w = (const float*)d_in[9];
    const float* Tv_b = (const float*)d_in[10];
    const float* Z1_w = (const float*)d_in[11];
    const float* Z1_b = (const float*)d_in[12];
    const float* Z2_w = (const float*)d_in[13];
    const float* Z2_b = (const float*)d_in[14];
    const float* O1_w = (const float*)d_in[15];
    const float* O1_b = (const float*)d_in[16];
    const float* O3_w = (const float*)d_in[17];
    const float* O3_b = (const float*)d_in[18];
    const float* R1_w = (const float*)d_in[19];
    const float* R1_b = (const float*)d_in[20];
    const float* R2_w = (const float*)d_in[21];
    const float* R2_b = (const float*)d_in[22];
    const float* FL_w = (const float*)d_in[23];
    const float* FL_b = (const float*)d_in[24];

    const int B = in_sizes[1] / NPIX;   // b0 is (B,32,32)

    hipLaunchKernelGGL(vin_fused, dim3(B), dim3(1024), 0, stream,
        map_in, b0, act_in, obs_in, step_p, vik_p,
        Tb_w, Tb_b, Tv_w, Tv_b, Z1_w, Z1_b, Z2_w, Z2_b,
        O1_w, O1_b, O3_w, O3_b, R1_w, R1_b, R2_w, R2_b,
        FL_w, FL_b, (float*)d_out, B);
}